// Round 1
// baseline (551.505 us; speedup 1.0000x reference)
//
#include <hip/hip_runtime.h>

// ---------------------------------------------------------------------------
// GCN block: 3x (GEMM -> degree-normalized aggregate), residual, relu.
// Strategy:
//   norm(src,dst) = dinv[src]*dinv[dst]; fold dinv[src] into GEMM epilogue
//   (hs = (x@W) * dinv_row), fold dinv[dst] into aggregation epilogue.
//   CSR-by-dst built per call (histogram + scan + bucket scatter) ->
//   atomic-free gather aggregation, one wave per node, lane = feature col.
// ---------------------------------------------------------------------------

// ---- edge dtype detection (int64 vs int32) --------------------------------
__global__ void detect64_kernel(const unsigned int* __restrict__ raw, int nwords,
                                int* __restrict__ flag) {
    int i = blockIdx.x * blockDim.x + threadIdx.x;
    if (i < nwords && (i & 1) && raw[i] != 0u) flag[0] = 0; // benign race
}

__global__ void convert_idx_kernel(const int* __restrict__ raw, int* __restrict__ out,
                                   int n, const int* __restrict__ flag) {
    int i = blockIdx.x * blockDim.x + threadIdx.x;
    if (i >= n) return;
    out[i] = flag[0] ? raw[2 * i] : raw[i];   // int64 little-endian low word
}

// ---- degree histogram + dinv ----------------------------------------------
__global__ void count_kernel(const int* __restrict__ dst, int* __restrict__ counts, int E) {
    int e = blockIdx.x * blockDim.x + threadIdx.x;
    if (e < E) atomicAdd(&counts[dst[e]], 1);
}

__global__ void dinv_kernel(const int* __restrict__ counts, float* __restrict__ dinv, int n) {
    int i = blockIdx.x * blockDim.x + threadIdx.x;
    if (i < n) dinv[i] = rsqrtf((float)(counts[i] + 1)); // +1 self loop, always > 0
}

// ---- exclusive scan of counts -> row_ptr (3 kernels) ----------------------
__global__ void scan1_kernel(const int* __restrict__ counts, int* __restrict__ row_ptr,
                             int* __restrict__ blockSums, int n) {
    __shared__ int s[256];
    int tid = threadIdx.x;
    int base = blockIdx.x * 1024 + tid * 4;
    int v0 = (base + 0 < n) ? counts[base + 0] : 0;
    int v1 = (base + 1 < n) ? counts[base + 1] : 0;
    int v2 = (base + 2 < n) ? counts[base + 2] : 0;
    int v3 = (base + 3 < n) ? counts[base + 3] : 0;
    int tsum = v0 + v1 + v2 + v3;
    s[tid] = tsum;
    __syncthreads();
    for (int off = 1; off < 256; off <<= 1) {
        int x = (tid >= off) ? s[tid - off] : 0;
        __syncthreads();
        if (tid >= off) s[tid] += x;
        __syncthreads();
    }
    int excl = s[tid] - tsum;
    if (base + 0 < n) row_ptr[base + 0] = excl;
    if (base + 1 < n) row_ptr[base + 1] = excl + v0;
    if (base + 2 < n) row_ptr[base + 2] = excl + v0 + v1;
    if (base + 3 < n) row_ptr[base + 3] = excl + v0 + v1 + v2;
    if (tid == 255) blockSums[blockIdx.x] = s[255];
}

__global__ void scan2_kernel(const int* __restrict__ blockSums, int* __restrict__ blockOffs,
                             int nb, int* __restrict__ rowPtrLast) {
    __shared__ int s[256];
    int tid = threadIdx.x;
    int v = (tid < nb) ? blockSums[tid] : 0;
    s[tid] = v;
    __syncthreads();
    for (int off = 1; off < 256; off <<= 1) {
        int x = (tid >= off) ? s[tid - off] : 0;
        __syncthreads();
        if (tid >= off) s[tid] += x;
        __syncthreads();
    }
    if (tid < nb) blockOffs[tid] = s[tid] - v;
    if (tid == 255) rowPtrLast[0] = s[255]; // row_ptr[N] = E
}

__global__ void scan3_kernel(int* __restrict__ row_ptr, const int* __restrict__ blockOffs, int n) {
    int i = blockIdx.x * blockDim.x + threadIdx.x;
    if (i < n) row_ptr[i] += blockOffs[i >> 10];
}

// ---- bucket scatter: CSR column (src) array -------------------------------
__global__ void scatter_kernel(const int* __restrict__ src, const int* __restrict__ dst,
                               const int* __restrict__ row_ptr, int* __restrict__ cursor,
                               int* __restrict__ col, int E) {
    int e = blockIdx.x * blockDim.x + threadIdx.x;
    if (e < E) {
        int d = dst[e];
        int pos = row_ptr[d] + atomicAdd(&cursor[d], 1);
        col[pos] = src[e];
    }
}

// ---- GEMM (N x K) @ (K x 64), epilogue-scaled by dinv[row] ----------------
// Block: 256 threads, tile 256 rows x 64 cols, thread tile 8x8.
// LDS: W natural [K][64] (32/16 KB), x transposed chunks sX[32][256] (32 KB).
// Hot LDS reads are 2-way bank aliased (free on CDNA4).
template <int K>
__global__ __launch_bounds__(256) void gemm_scaled_kernel(
        const float* __restrict__ A, const float* __restrict__ W,
        const float* __restrict__ dinv, float* __restrict__ out, int nrows) {
    __shared__ float sW[K * 64];
    __shared__ float sX[32 * 256];
    int tid = threadIdx.x;
    int rowBase = blockIdx.x * 256;
    for (int i = tid * 4; i < K * 64; i += 1024)
        *(float4*)&sW[i] = *(const float4*)&W[i];
    int c0 = (tid & 7) * 8;
    int r0 = (tid >> 3) * 8;
    float acc[8][8];
#pragma unroll
    for (int r = 0; r < 8; r++)
#pragma unroll
        for (int c = 0; c < 8; c++) acc[r][c] = 0.f;

    for (int kb = 0; kb < K; kb += 32) {
        __syncthreads();
        {
            int row = tid; // 0..255
            int grow = rowBase + row;
            if (grow >= nrows) grow = nrows - 1;
            const float* srcp = A + (size_t)grow * K + kb;
#pragma unroll
            for (int j = 0; j < 8; j++) {
                float4 v = *(const float4*)(srcp + j * 4);
                sX[(j * 4 + 0) * 256 + row] = v.x;
                sX[(j * 4 + 1) * 256 + row] = v.y;
                sX[(j * 4 + 2) * 256 + row] = v.z;
                sX[(j * 4 + 3) * 256 + row] = v.w;
            }
        }
        __syncthreads();
#pragma unroll
        for (int k = 0; k < 32; k++) {
            float xv[8], wv[8];
            *(float4*)&xv[0] = *(float4*)&sX[k * 256 + r0];
            *(float4*)&xv[4] = *(float4*)&sX[k * 256 + r0 + 4];
            *(float4*)&wv[0] = *(float4*)&sW[(kb + k) * 64 + c0];
            *(float4*)&wv[4] = *(float4*)&sW[(kb + k) * 64 + c0 + 4];
#pragma unroll
            for (int r = 0; r < 8; r++)
#pragma unroll
                for (int c = 0; c < 8; c++)
                    acc[r][c] = fmaf(xv[r], wv[c], acc[r][c]);
        }
    }
#pragma unroll
    for (int r = 0; r < 8; r++) {
        int grow = rowBase + r0 + r;
        if (grow < nrows) {
            float sc = dinv[grow];
            float4 o0 = make_float4(acc[r][0] * sc, acc[r][1] * sc, acc[r][2] * sc, acc[r][3] * sc);
            float4 o1 = make_float4(acc[r][4] * sc, acc[r][5] * sc, acc[r][6] * sc, acc[r][7] * sc);
            *(float4*)&out[(size_t)grow * 64 + c0] = o0;
            *(float4*)&out[(size_t)grow * 64 + c0 + 4] = o1;
        }
    }
}

// ---- aggregation: one wave per node, lane = feature column ----------------
// out[n] = dinv[n] * (hs[n] + sum_{e in adj(n)} hs[col[e]]) + bias
// (+ optional relu, optional residual add)
__global__ __launch_bounds__(256) void aggregate_kernel(
        const float* __restrict__ hs, const float* __restrict__ dinv,
        const float* __restrict__ bias, const int* __restrict__ col,
        const int* __restrict__ row_ptr, const float* __restrict__ resid,
        float* __restrict__ out, int n, int relu) {
    int wave = (blockIdx.x * blockDim.x + threadIdx.x) >> 6;
    int lane = threadIdx.x & 63;
    if (wave >= n) return;
    int start = row_ptr[wave];
    int end = row_ptr[wave + 1];
    float acc = hs[(size_t)wave * 64 + lane]; // self-loop term (pre-scaled)
    int e = start;
    while (e < end) {
        int cnt = end - e;
        if (cnt > 64) cnt = 64;
        int myidx = (lane < cnt) ? col[e + lane] : 0;
        int j = 0;
        for (; j + 4 <= cnt; j += 4) {
            int s0 = __shfl(myidx, j + 0);
            int s1 = __shfl(myidx, j + 1);
            int s2 = __shfl(myidx, j + 2);
            int s3 = __shfl(myidx, j + 3);
            float v0 = hs[(size_t)s0 * 64 + lane];
            float v1 = hs[(size_t)s1 * 64 + lane];
            float v2 = hs[(size_t)s2 * 64 + lane];
            float v3 = hs[(size_t)s3 * 64 + lane];
            acc += v0 + v1 + v2 + v3;
        }
        for (; j < cnt; j++) {
            int s = __shfl(myidx, j);
            acc += hs[(size_t)s * 64 + lane];
        }
        e += cnt;
    }
    float o = dinv[wave] * acc + bias[lane];
    if (relu) o = fmaxf(o, 0.f);
    if (resid) o += resid[(size_t)wave * 64 + lane];
    out[(size_t)wave * 64 + lane] = o;
}

// ---------------------------------------------------------------------------
extern "C" void kernel_launch(void* const* d_in, const int* in_sizes, int n_in,
                              void* d_out, int out_size, void* d_ws, size_t ws_size,
                              hipStream_t stream) {
    const float* x  = (const float*)d_in[0];
    const int*   ei = (const int*)d_in[1];
    const float* W0 = (const float*)d_in[2];
    const float* b0 = (const float*)d_in[3];
    const float* Ws = (const float*)d_in[4];
    const float* bs = (const float*)d_in[5];
    float* out = (float*)d_out;

    const int N = in_sizes[0] / 128;
    const int E = in_sizes[1] / 2;

    char* p = (char*)d_ws;
    auto carve = [&](size_t bytes) {
        char* r = p;
        p += (bytes + 255) & ~(size_t)255;
        return r;
    };
    int*   flag      = (int*)carve(4);
    int*   idx32     = (int*)carve((size_t)2 * E * 4);
    int*   counts    = (int*)carve((size_t)2 * N * 4); // counts + cursor, zeroed together
    int*   cursor    = counts + N;
    float* dinv      = (float*)carve((size_t)N * 4);
    int*   row_ptr   = (int*)carve((size_t)(N + 1) * 4);
    int*   blockSums = (int*)carve(256 * 4);
    int*   blockOffs = (int*)carve(256 * 4);
    int*   col       = (int*)carve((size_t)E * 4);
    float* hs        = (float*)carve((size_t)N * 64 * 4);
    float* xt        = (float*)carve((size_t)N * 64 * 4);
    float* h         = (float*)carve((size_t)N * 64 * 4);

    hipMemsetAsync(flag, 1, 4, stream);                       // nonzero = "int64"
    hipMemsetAsync(counts, 0, (size_t)2 * N * 4, stream);

    detect64_kernel<<<(2 * E + 255) / 256, 256, 0, stream>>>((const unsigned int*)ei, 2 * E, flag);
    convert_idx_kernel<<<(2 * E + 255) / 256, 256, 0, stream>>>(ei, idx32, 2 * E, flag);
    const int* src = idx32;
    const int* dst = idx32 + E;

    count_kernel<<<(E + 255) / 256, 256, 0, stream>>>(dst, counts, E);
    dinv_kernel<<<(N + 255) / 256, 256, 0, stream>>>(counts, dinv, N);

    int nb = (N + 1023) / 1024;
    scan1_kernel<<<nb, 256, 0, stream>>>(counts, row_ptr, blockSums, N);
    scan2_kernel<<<1, 256, 0, stream>>>(blockSums, blockOffs, nb, row_ptr + N);
    scan3_kernel<<<(N + 255) / 256, 256, 0, stream>>>(row_ptr, blockOffs, N);
    scatter_kernel<<<(E + 255) / 256, 256, 0, stream>>>(src, dst, row_ptr, cursor, col, E);

    int gblocks = (N + 255) / 256;
    int ablocks = (N + 3) / 4;
    // layer 1: x_temp = agg(x @ W0) + b0            (no relu)
    gemm_scaled_kernel<128><<<gblocks, 256, 0, stream>>>(x, W0, dinv, hs, N);
    aggregate_kernel<<<ablocks, 256, 0, stream>>>(hs, dinv, b0, col, row_ptr, nullptr, xt, N, 0);
    // layer 2: h = relu(agg(xt @ Ws[0]) + bs[0])
    gemm_scaled_kernel<64><<<gblocks, 256, 0, stream>>>(xt, Ws, dinv, hs, N);
    aggregate_kernel<<<ablocks, 256, 0, stream>>>(hs, dinv, bs, col, row_ptr, nullptr, h, N, 1);
    // layer 3: out = relu(agg(h @ Ws[1]) + bs[1]) + xt
    gemm_scaled_kernel<64><<<gblocks, 256, 0, stream>>>(h, Ws + 64 * 64, dinv, hs, N);
    aggregate_kernel<<<ablocks, 256, 0, stream>>>(hs, dinv, bs + 64, col, row_ptr, xt, out, N, 1);
}